// Round 3
// baseline (299.326 us; speedup 1.0000x reference)
//
#include <hip/hip_runtime.h>
#include <math.h>

#define NMOD 4
#define BB   8
#define NN   4096
#define MM   4608
#define TPB  256

// ---- fast path geometry ----
#define QPT      4                      // queries per thread
#define QPB      (TPB * QPT)            // 1024 queries per block
#define NXB      (NN / QPB)             // 4
#define SLICES   16
#define SLICE_M  (MM / SLICES)          // 288
#define SPAIRS   (SLICE_M / 2)          // 144
#define QCOUNT   (NMOD * BB * NN)       // 131072 query-instances
#define KEY_BYTES ((size_t)SLICES * QCOUNT * 8)      // 16.78 MB
#define NXBLK2   (NN / TPB)             // 16
#define NPART    (NMOD * BB * NXBLK2)   // 512
#define WS_FAST  (KEY_BYTES + NPART * sizeof(float))
#define WS_MID   ((size_t)QCOUNT * 8 + NPART * sizeof(float))

typedef float v2f __attribute__((ext_vector_type(2)));

// ---------------- pass 1: Q4-blocked slice argmin --------------------------
// ATOMIC=false: write own slot keys[sl*QCOUNT + q]  (no init needed)
// ATOMIC=true : atomicMin into keys[q]              (needs 0xFF memset)
template <bool ATOMIC>
__global__ __launch_bounds__(TPB, 8) void nn_min_kernel(
    const float* __restrict__ noisy, const float* __restrict__ clean,
    const float* __restrict__ seeds, const float* __restrict__ stds,
    const float* __restrict__ disp,  const float* __restrict__ noise,
    unsigned long long* __restrict__ keys)
{
    __shared__ float4 txy[SPAIRS];   // {x0,x1,y0,y1}
    __shared__ float4 tzw[SPAIRS];   // {z0,z1,w0,w1}, w = ||t||^2

    const int tid   = threadIdx.x;
    const int b     = blockIdx.y;
    const int mod   = blockIdx.z >> 4;
    const int sl    = blockIdx.z & 15;
    const int mbase = sl * SLICE_M;
    const int nb    = blockIdx.x * QPB + tid;

    const float sx = seeds[b * 3 + 0];
    const float sy = seeds[b * 3 + 1];
    const float sz = seeds[b * 3 + 2];
    float nstd = 0.0f;
    if (mod == 0) nstd = stds[b] * 0.25f;
    else if (mod == 1) nstd = stds[b] * 0.0625f;
    const bool nt = (mod < 2);

    // stage this 288-target slice as pair-interleaved SoA
    for (int k = tid; k < SLICE_M; k += TPB) {
        const int m = mbase + k;
        const size_t oc = ((size_t)b * MM + m) * 3;
        float tx = clean[oc + 0] - sx;
        float ty = clean[oc + 1] - sy;
        float tz = clean[oc + 2] - sz;
        if (nt) {
            const size_t on = (((size_t)mod * BB + b) * MM + m) * 3;
            tx = fmaf(noise[on + 0], nstd, tx);
            ty = fmaf(noise[on + 1], nstd, ty);
            tz = fmaf(noise[on + 2], nstd, tz);
        }
        const float tw = fmaf(tx, tx, fmaf(ty, ty, tz * tz));
        float* pxy = (float*)&txy[k >> 1];
        float* pzw = (float*)&tzw[k >> 1];
        const int h = k & 1;
        pxy[0 + h] = tx; pxy[2 + h] = ty;
        pzw[0 + h] = tz; pzw[2 + h] = tw;
    }

    // 4 queries per thread (stride TPB for coalescing)
    float m2x[QPT], m2y[QPT], m2z[QPT];
    #pragma unroll
    for (int qq = 0; qq < QPT; ++qq) {
        const int n = nb + qq * TPB;
        float qx = noisy[((size_t)b * NN + n) * 3 + 0] - sx;
        float qy = noisy[((size_t)b * NN + n) * 3 + 1] - sy;
        float qz = noisy[((size_t)b * NN + n) * 3 + 2] - sz;
        for (int j = 0; j < mod; ++j) {
            const size_t o = (((size_t)j * BB + b) * NN + n) * 3;
            qx += disp[o + 0]; qy += disp[o + 1]; qz += disp[o + 2];
        }
        m2x[qq] = -2.0f * qx; m2y[qq] = -2.0f * qy; m2z[qq] = -2.0f * qz;
    }

    __syncthreads();

    float bestA[QPT], bestB[QPT];
    int   idxA[QPT], idxB[QPT];
    #pragma unroll
    for (int qq = 0; qq < QPT; ++qq) {
        bestA[qq] = INFINITY; bestB[qq] = INFINITY;
        idxA[qq] = 0; idxB[qq] = 0;
    }

    #pragma unroll 4
    for (int p = 0; p < SPAIRS; ++p) {
        const float4 a = txy[p];
        const float4 c = tzw[p];
        const v2f xs = {a.x, a.y};
        const v2f ys = {a.z, a.w};
        const v2f zs = {c.x, c.y};
        const v2f ws = {c.z, c.w};
        #pragma unroll
        for (int qq = 0; qq < QPT; ++qq) {
            const v2f vx = {m2x[qq], m2x[qq]};
            const v2f vy = {m2y[qq], m2y[qq]};
            const v2f vz = {m2z[qq], m2z[qq]};
            const v2f d2 = __builtin_elementwise_fma(vx, xs,
                            __builtin_elementwise_fma(vy, ys,
                             __builtin_elementwise_fma(vz, zs, ws)));
            const bool ca = d2.x < bestA[qq];
            bestA[qq] = ca ? d2.x : bestA[qq];
            idxA[qq]  = ca ? p    : idxA[qq];
            const bool cb = d2.y < bestB[qq];
            bestB[qq] = cb ? d2.y : bestB[qq];
            idxB[qq]  = cb ? p    : idxB[qq];
        }
    }

    #pragma unroll
    for (int qq = 0; qq < QPT; ++qq) {
        float best = bestA[qq]; int bi = idxA[qq] * 2;
        if (bestB[qq] < best) { best = bestB[qq]; bi = idxB[qq] * 2 + 1; }
        // recover q2 from -2q: q2 = (m2x^2+m2y^2+m2z^2)/4
        const float q2 = 0.25f * fmaf(m2x[qq], m2x[qq],
                             fmaf(m2y[qq], m2y[qq], m2z[qq] * m2z[qq]));
        const float f = best + q2 + 8.0f;   // > 0, order-preserving per query
        const unsigned long long key =
            ((unsigned long long)__float_as_uint(f) << 32) |
            (unsigned int)(mbase + bi);
        const size_t q = (((size_t)mod * BB + b) * NN) + (nb + qq * TPB);
        if (ATOMIC) atomicMin(&keys[q], key);
        else        keys[(size_t)sl * QCOUNT + q] = key;
    }
}

// ---------------- pass 2: combine slices, unpack winner, loss ---------------
__global__ __launch_bounds__(TPB) void nn_loss_pass2(
    const float* __restrict__ noisy, const float* __restrict__ clean,
    const float* __restrict__ seeds, const float* __restrict__ stds,
    const float* __restrict__ disp,  const float* __restrict__ noise,
    const unsigned long long* __restrict__ keys, int nslices,
    float* __restrict__ partials)
{
    __shared__ float red[TPB / 64];
    const int tid = threadIdx.x;
    const int b   = blockIdx.y;
    const int mod = blockIdx.z;
    const int n   = blockIdx.x * TPB + tid;

    const float sx = seeds[b * 3 + 0];
    const float sy = seeds[b * 3 + 1];
    const float sz = seeds[b * 3 + 2];
    float nstd = 0.0f;
    if (mod == 0) nstd = stds[b] * 0.25f;
    else if (mod == 1) nstd = stds[b] * 0.0625f;

    float qx = noisy[((size_t)b * NN + n) * 3 + 0] - sx;
    float qy = noisy[((size_t)b * NN + n) * 3 + 1] - sy;
    float qz = noisy[((size_t)b * NN + n) * 3 + 2] - sz;
    for (int j = 0; j < mod; ++j) {
        const size_t o = (((size_t)j * BB + b) * NN + n) * 3;
        qx += disp[o + 0]; qy += disp[o + 1]; qz += disp[o + 2];
    }
    const size_t od = (((size_t)mod * BB + b) * NN + n) * 3;
    const float dxp = disp[od + 0];
    const float dyp = disp[od + 1];
    const float dzp = disp[od + 2];

    const size_t q = (((size_t)mod * BB + b) * NN) + n;
    unsigned long long k = keys[q];
    for (int s = 1; s < nslices; ++s) {
        const unsigned long long v = keys[(size_t)s * QCOUNT + q];
        k = v < k ? v : k;
    }
    const unsigned gidx = (unsigned)(k & 0xFFFFFFFFull);

    const size_t oc = ((size_t)b * MM + gidx) * 3;
    float tx = clean[oc + 0] - sx;
    float ty = clean[oc + 1] - sy;
    float tz = clean[oc + 2] - sz;
    if (mod < 2) {
        const size_t on = (((size_t)mod * BB + b) * MM + gidx) * 3;
        tx = fmaf(noise[on + 0], nstd, tx);
        ty = fmaf(noise[on + 1], nstd, ty);
        tz = fmaf(noise[on + 2], nstd, tz);
    }
    const float ex = dxp - (tx - qx);
    const float ey = dyp - (ty - qy);
    const float ez = dzp - (tz - qz);
    float v = fmaf(ex, ex, fmaf(ey, ey, ez * ez));

    for (int o = 32; o; o >>= 1) v += __shfl_down(v, o);
    if ((tid & 63) == 0) red[tid >> 6] = v;
    __syncthreads();
    if (tid == 0) {
        const float s = red[0] + red[1] + red[2] + red[3];
        partials[(((size_t)mod * BB + b) * NXBLK2) + blockIdx.x] = s;
    }
}

__global__ void finalize_kernel(const float* __restrict__ partials, float* __restrict__ out) {
    float s = 0.0f;
    for (int k = threadIdx.x; k < NPART; k += 64) s += partials[k];
    for (int o = 32; o; o >>= 1) s += __shfl_down(s, o);
    if (threadIdx.x == 0) {
        out[0] = s * (1.0f / BB);
        out[1] = s * (1.0f / BB);
    }
}

// ---------------- monolithic fallback (needs only 2 KiB ws) -----------------
#define TM 768
__global__ __launch_bounds__(TPB) void nn_loss_kernel(
    const float* __restrict__ noisy, const float* __restrict__ clean,
    const float* __restrict__ seeds, const float* __restrict__ stds,
    const float* __restrict__ disp,  const float* __restrict__ noise,
    float* __restrict__ partials)
{
    __shared__ float4 tgt[TM];
    __shared__ float red[TPB / 64];
    const int tid = threadIdx.x;
    const int b = blockIdx.y, mod = blockIdx.z;
    const int n = blockIdx.x * TPB + tid;
    const float sx = seeds[b*3+0], sy = seeds[b*3+1], sz = seeds[b*3+2];
    float qx = noisy[((size_t)b*NN+n)*3+0] - sx;
    float qy = noisy[((size_t)b*NN+n)*3+1] - sy;
    float qz = noisy[((size_t)b*NN+n)*3+2] - sz;
    for (int j = 0; j < mod; ++j) {
        const size_t o = (((size_t)j*BB + b)*NN + n)*3;
        qx += disp[o+0]; qy += disp[o+1]; qz += disp[o+2];
    }
    const size_t od = (((size_t)mod*BB + b)*NN + n)*3;
    const float dxp = disp[od+0], dyp = disp[od+1], dzp = disp[od+2];
    float nstd = 0.0f;
    if (mod == 0) nstd = stds[b]*0.25f; else if (mod == 1) nstd = stds[b]*0.0625f;
    const bool nt = (mod < 2);
    const float m2x = -2.0f*qx, m2y = -2.0f*qy, m2z = -2.0f*qz;
    float best = INFINITY; int bestm = 0;
    for (int mt = 0; mt < MM; mt += TM) {
        __syncthreads();
        for (int k = tid; k < TM; k += TPB) {
            const int m = mt + k;
            const size_t oc = ((size_t)b*MM + m)*3;
            float tx = clean[oc+0]-sx, ty = clean[oc+1]-sy, tz = clean[oc+2]-sz;
            if (nt) {
                const size_t on = (((size_t)mod*BB + b)*MM + m)*3;
                tx = fmaf(noise[on+0], nstd, tx);
                ty = fmaf(noise[on+1], nstd, ty);
                tz = fmaf(noise[on+2], nstd, tz);
            }
            tgt[k] = make_float4(tx, ty, tz, fmaf(tx,tx,fmaf(ty,ty,tz*tz)));
        }
        __syncthreads();
        #pragma unroll 8
        for (int k = 0; k < TM; ++k) {
            const float4 t = tgt[k];
            const float d2 = fmaf(m2x, t.x, fmaf(m2y, t.y, fmaf(m2z, t.z, t.w)));
            if (d2 < best) { best = d2; bestm = mt + k; }
        }
    }
    const size_t oc = ((size_t)b*MM + bestm)*3;
    float tx = clean[oc+0]-sx, ty = clean[oc+1]-sy, tz = clean[oc+2]-sz;
    if (nt) {
        const size_t on = (((size_t)mod*BB + b)*MM + bestm)*3;
        tx = fmaf(noise[on+0], nstd, tx);
        ty = fmaf(noise[on+1], nstd, ty);
        tz = fmaf(noise[on+2], nstd, tz);
    }
    const float ex = dxp - (tx - qx), ey = dyp - (ty - qy), ez = dzp - (tz - qz);
    float v = fmaf(ex, ex, fmaf(ey, ey, ez*ez));
    for (int o = 32; o; o >>= 1) v += __shfl_down(v, o);
    if ((tid & 63) == 0) red[tid >> 6] = v;
    __syncthreads();
    if (tid == 0)
        partials[(((size_t)mod*BB + b)*NXBLK2) + blockIdx.x] = red[0]+red[1]+red[2]+red[3];
}

extern "C" void kernel_launch(void* const* d_in, const int* in_sizes, int n_in,
                              void* d_out, int out_size, void* d_ws, size_t ws_size,
                              hipStream_t stream) {
    const float* noisy = (const float*)d_in[0];
    const float* clean = (const float*)d_in[1];
    const float* seeds = (const float*)d_in[2];
    const float* stds  = (const float*)d_in[3];
    const float* disp  = (const float*)d_in[4];
    const float* noise = (const float*)d_in[5];
    float* out = (float*)d_out;

    if (ws_size >= WS_FAST) {
        unsigned long long* keys = (unsigned long long*)d_ws;
        float* partials = (float*)((char*)d_ws + KEY_BYTES);
        dim3 g1(NXB, BB, NMOD * SLICES);
        nn_min_kernel<false><<<g1, TPB, 0, stream>>>(noisy, clean, seeds, stds, disp, noise, keys);
        dim3 g2(NXBLK2, BB, NMOD);
        nn_loss_pass2<<<g2, TPB, 0, stream>>>(noisy, clean, seeds, stds, disp, noise, keys, SLICES, partials);
        finalize_kernel<<<1, 64, 0, stream>>>(partials, out);
    } else if (ws_size >= WS_MID) {
        unsigned long long* keys = (unsigned long long*)d_ws;
        float* partials = (float*)((char*)d_ws + (size_t)QCOUNT * 8);
        hipMemsetAsync(d_ws, 0xFF, (size_t)QCOUNT * 8, stream);
        dim3 g1(NXB, BB, NMOD * SLICES);
        nn_min_kernel<true><<<g1, TPB, 0, stream>>>(noisy, clean, seeds, stds, disp, noise, keys);
        dim3 g2(NXBLK2, BB, NMOD);
        nn_loss_pass2<<<g2, TPB, 0, stream>>>(noisy, clean, seeds, stds, disp, noise, keys, 1, partials);
        finalize_kernel<<<1, 64, 0, stream>>>(partials, out);
    } else {
        float* partials = (float*)d_ws;
        dim3 grid(NXBLK2, BB, NMOD);
        nn_loss_kernel<<<grid, TPB, 0, stream>>>(noisy, clean, seeds, stds, disp, noise, partials);
        finalize_kernel<<<1, 64, 0, stream>>>(partials, out);
    }
}

// Round 4
// 97.034 us; speedup vs baseline: 3.0848x; 3.0848x over previous
//
#include <hip/hip_runtime.h>
#include <math.h>

#define NMOD 4
#define BB   8
#define NN   4096
#define MM   4608
#define TPB  256

// ---- fast path geometry ----
#define QPT      8                      // queries per thread (hand-unrolled scalars!)
#define QPB      (TPB * QPT)            // 2048 queries per block
#define NXB      (NN / QPB)             // 2
#define SLICES   16
#define SLICE_M  (MM / SLICES)          // 288
#define SPAIRS   (SLICE_M / 2)          // 144
#define QCOUNT   (NMOD * BB * NN)       // 131072
#define KEYB     ((size_t)QCOUNT * 8)   // 1 MiB packed keys
#define NXBLK2   (NN / TPB)             // 16
#define NPART    (NMOD * BB * NXBLK2)   // 512
#define WS_NEED  (KEYB + NPART * sizeof(float))

typedef float v2f __attribute__((ext_vector_type(2)));

// ---------------- pass 1: 8-query register-blocked slice argmin -------------
__global__ __launch_bounds__(TPB, 4) void nn_min_kernel(
    const float* __restrict__ noisy, const float* __restrict__ clean,
    const float* __restrict__ seeds, const float* __restrict__ stds,
    const float* __restrict__ disp,  const float* __restrict__ noise,
    unsigned long long* __restrict__ keys)
{
    __shared__ float4 txy[SPAIRS];   // {x0,x1,y0,y1}
    __shared__ float4 tzw[SPAIRS];   // {z0,z1,w0,w1}, w = ||t||^2

    const int tid   = threadIdx.x;
    const int b     = blockIdx.y;
    const int mod   = blockIdx.z >> 4;
    const int sl    = blockIdx.z & 15;
    const int mbase = sl * SLICE_M;
    const int nb    = blockIdx.x * QPB + tid;

    const float sx = seeds[b * 3 + 0];
    const float sy = seeds[b * 3 + 1];
    const float sz = seeds[b * 3 + 2];
    float nstd = 0.0f;
    if (mod == 0) nstd = stds[b] * 0.25f;
    else if (mod == 1) nstd = stds[b] * 0.0625f;
    const bool nt = (mod < 2);

    // stage this 288-target slice as pair-interleaved SoA
    for (int k = tid; k < SLICE_M; k += TPB) {
        const int m = mbase + k;
        const size_t oc = ((size_t)b * MM + m) * 3;
        float tx = clean[oc + 0] - sx;
        float ty = clean[oc + 1] - sy;
        float tz = clean[oc + 2] - sz;
        if (nt) {
            const size_t on = (((size_t)mod * BB + b) * MM + m) * 3;
            tx = fmaf(noise[on + 0], nstd, tx);
            ty = fmaf(noise[on + 1], nstd, ty);
            tz = fmaf(noise[on + 2], nstd, tz);
        }
        const float tw = fmaf(tx, tx, fmaf(ty, ty, tz * tz));
        float* pxy = (float*)&txy[k >> 1];
        float* pzw = (float*)&tzw[k >> 1];
        const int h = k & 1;
        pxy[0 + h] = tx; pxy[2 + h] = ty;
        pzw[0 + h] = tz; pzw[2 + h] = tw;
    }

    // ---- 8 queries, all named scalars (NO arrays -> no scratch) ----
    float m2x0, m2y0, m2z0, m2x1, m2y1, m2z1, m2x2, m2y2, m2z2, m2x3, m2y3, m2z3;
    float m2x4, m2y4, m2z4, m2x5, m2y5, m2z5, m2x6, m2y6, m2z6, m2x7, m2y7, m2z7;

#define QSETUP(K, MX, MY, MZ) do {                                        \
        const int n = nb + (K) * TPB;                                     \
        const size_t o0 = ((size_t)b * NN + n) * 3;                       \
        float qx = noisy[o0 + 0] - sx;                                    \
        float qy = noisy[o0 + 1] - sy;                                    \
        float qz = noisy[o0 + 2] - sz;                                    \
        for (int j = 0; j < mod; ++j) {                                   \
            const size_t o = (((size_t)j * BB + b) * NN + n) * 3;         \
            qx += disp[o + 0]; qy += disp[o + 1]; qz += disp[o + 2];      \
        }                                                                 \
        MX = -2.0f * qx; MY = -2.0f * qy; MZ = -2.0f * qz;                \
    } while (0)

    QSETUP(0, m2x0, m2y0, m2z0); QSETUP(1, m2x1, m2y1, m2z1);
    QSETUP(2, m2x2, m2y2, m2z2); QSETUP(3, m2x3, m2y3, m2z3);
    QSETUP(4, m2x4, m2y4, m2z4); QSETUP(5, m2x5, m2y5, m2z5);
    QSETUP(6, m2x6, m2y6, m2z6); QSETUP(7, m2x7, m2y7, m2z7);
#undef QSETUP

    __syncthreads();

    float bA0 = INFINITY, bB0 = INFINITY, bA1 = INFINITY, bB1 = INFINITY;
    float bA2 = INFINITY, bB2 = INFINITY, bA3 = INFINITY, bB3 = INFINITY;
    float bA4 = INFINITY, bB4 = INFINITY, bA5 = INFINITY, bB5 = INFINITY;
    float bA6 = INFINITY, bB6 = INFINITY, bA7 = INFINITY, bB7 = INFINITY;
    int iA0 = 0, iB0 = 0, iA1 = 0, iB1 = 0, iA2 = 0, iB2 = 0, iA3 = 0, iB3 = 0;
    int iA4 = 0, iB4 = 0, iA5 = 0, iB5 = 0, iA6 = 0, iB6 = 0, iA7 = 0, iB7 = 0;

    #pragma unroll 2
    for (int p = 0; p < SPAIRS; ++p) {
        const float4 a = txy[p];
        const float4 c = tzw[p];
        const v2f xs = {a.x, a.y};
        const v2f ys = {a.z, a.w};
        const v2f zs = {c.x, c.y};
        const v2f ws = {c.z, c.w};

#define EVAL(MX, MY, MZ, BA, IA, BBv, IB) do {                            \
        const v2f vx = {MX, MX};                                          \
        const v2f vy = {MY, MY};                                          \
        const v2f vz = {MZ, MZ};                                          \
        const v2f d2 = __builtin_elementwise_fma(vx, xs,                  \
                        __builtin_elementwise_fma(vy, ys,                 \
                         __builtin_elementwise_fma(vz, zs, ws)));         \
        const bool ca = d2.x < BA;                                        \
        BA = ca ? d2.x : BA;  IA = ca ? p : IA;                           \
        const bool cb = d2.y < BBv;                                       \
        BBv = cb ? d2.y : BBv;  IB = cb ? p : IB;                         \
    } while (0)

        EVAL(m2x0, m2y0, m2z0, bA0, iA0, bB0, iB0);
        EVAL(m2x1, m2y1, m2z1, bA1, iA1, bB1, iB1);
        EVAL(m2x2, m2y2, m2z2, bA2, iA2, bB2, iB2);
        EVAL(m2x3, m2y3, m2z3, bA3, iA3, bB3, iB3);
        EVAL(m2x4, m2y4, m2z4, bA4, iA4, bB4, iB4);
        EVAL(m2x5, m2y5, m2z5, bA5, iA5, bB5, iB5);
        EVAL(m2x6, m2y6, m2z6, bA6, iA6, bB6, iB6);
        EVAL(m2x7, m2y7, m2z7, bA7, iA7, bB7, iB7);
#undef EVAL
    }

    const size_t qbase = (((size_t)mod * BB + b) * NN);

#define FINISH(K, MX, MY, MZ, BA, IA, BBv, IB) do {                       \
        float best = BA; int bi = (IA) * 2;                               \
        if (BBv < best) { best = BBv; bi = (IB) * 2 + 1; }                \
        const float q2 = 0.25f * fmaf(MX, MX, fmaf(MY, MY, (MZ) * (MZ)));\
        const float f = best + q2 + 8.0f;                                 \
        const unsigned long long key =                                    \
            ((unsigned long long)__float_as_uint(f) << 32) |              \
            (unsigned int)(mbase + bi);                                   \
        atomicMin(&keys[qbase + (size_t)(nb + (K) * TPB)], key);          \
    } while (0)

    FINISH(0, m2x0, m2y0, m2z0, bA0, iA0, bB0, iB0);
    FINISH(1, m2x1, m2y1, m2z1, bA1, iA1, bB1, iB1);
    FINISH(2, m2x2, m2y2, m2z2, bA2, iA2, bB2, iB2);
    FINISH(3, m2x3, m2y3, m2z3, bA3, iA3, bB3, iB3);
    FINISH(4, m2x4, m2y4, m2z4, bA4, iA4, bB4, iB4);
    FINISH(5, m2x5, m2y5, m2z5, bA5, iA5, bB5, iB5);
    FINISH(6, m2x6, m2y6, m2z6, bA6, iA6, bB6, iB6);
    FINISH(7, m2x7, m2y7, m2z7, bA7, iA7, bB7, iB7);
#undef FINISH
}

// ---------------- pass 2: unpack winner, compute loss terms -----------------
__global__ __launch_bounds__(TPB) void nn_loss_pass2(
    const float* __restrict__ noisy, const float* __restrict__ clean,
    const float* __restrict__ seeds, const float* __restrict__ stds,
    const float* __restrict__ disp,  const float* __restrict__ noise,
    const unsigned long long* __restrict__ keys,
    float* __restrict__ partials)
{
    __shared__ float red[TPB / 64];
    const int tid = threadIdx.x;
    const int b   = blockIdx.y;
    const int mod = blockIdx.z;
    const int n   = blockIdx.x * TPB + tid;

    const float sx = seeds[b * 3 + 0];
    const float sy = seeds[b * 3 + 1];
    const float sz = seeds[b * 3 + 2];
    float nstd = 0.0f;
    if (mod == 0) nstd = stds[b] * 0.25f;
    else if (mod == 1) nstd = stds[b] * 0.0625f;

    float qx = noisy[((size_t)b * NN + n) * 3 + 0] - sx;
    float qy = noisy[((size_t)b * NN + n) * 3 + 1] - sy;
    float qz = noisy[((size_t)b * NN + n) * 3 + 2] - sz;
    for (int j = 0; j < mod; ++j) {
        const size_t o = (((size_t)j * BB + b) * NN + n) * 3;
        qx += disp[o + 0]; qy += disp[o + 1]; qz += disp[o + 2];
    }
    const size_t od = (((size_t)mod * BB + b) * NN + n) * 3;
    const float dxp = disp[od + 0];
    const float dyp = disp[od + 1];
    const float dzp = disp[od + 2];

    const unsigned gidx =
        (unsigned)(keys[(((size_t)mod * BB + b) * NN) + n] & 0xFFFFFFFFull);

    const size_t oc = ((size_t)b * MM + gidx) * 3;
    float tx = clean[oc + 0] - sx;
    float ty = clean[oc + 1] - sy;
    float tz = clean[oc + 2] - sz;
    if (mod < 2) {
        const size_t on = (((size_t)mod * BB + b) * MM + gidx) * 3;
        tx = fmaf(noise[on + 0], nstd, tx);
        ty = fmaf(noise[on + 1], nstd, ty);
        tz = fmaf(noise[on + 2], nstd, tz);
    }
    const float ex = dxp - (tx - qx);
    const float ey = dyp - (ty - qy);
    const float ez = dzp - (tz - qz);
    float v = fmaf(ex, ex, fmaf(ey, ey, ez * ez));

    for (int o = 32; o; o >>= 1) v += __shfl_down(v, o);
    if ((tid & 63) == 0) red[tid >> 6] = v;
    __syncthreads();
    if (tid == 0) {
        const float s = red[0] + red[1] + red[2] + red[3];
        partials[(((size_t)mod * BB + b) * NXBLK2) + blockIdx.x] = s;
    }
}

__global__ void finalize_kernel(const float* __restrict__ partials, float* __restrict__ out) {
    float s = 0.0f;
    for (int k = threadIdx.x; k < NPART; k += 64) s += partials[k];
    for (int o = 32; o; o >>= 1) s += __shfl_down(s, o);
    if (threadIdx.x == 0) {
        out[0] = s * (1.0f / BB);
        out[1] = s * (1.0f / BB);
    }
}

// ---------------- monolithic fallback (needs only 2 KiB ws) -----------------
#define TM 768
__global__ __launch_bounds__(TPB) void nn_loss_kernel(
    const float* __restrict__ noisy, const float* __restrict__ clean,
    const float* __restrict__ seeds, const float* __restrict__ stds,
    const float* __restrict__ disp,  const float* __restrict__ noise,
    float* __restrict__ partials)
{
    __shared__ float4 tgt[TM];
    __shared__ float red[TPB / 64];
    const int tid = threadIdx.x;
    const int b = blockIdx.y, mod = blockIdx.z;
    const int n = blockIdx.x * TPB + tid;
    const float sx = seeds[b*3+0], sy = seeds[b*3+1], sz = seeds[b*3+2];
    float qx = noisy[((size_t)b*NN+n)*3+0] - sx;
    float qy = noisy[((size_t)b*NN+n)*3+1] - sy;
    float qz = noisy[((size_t)b*NN+n)*3+2] - sz;
    for (int j = 0; j < mod; ++j) {
        const size_t o = (((size_t)j*BB + b)*NN + n)*3;
        qx += disp[o+0]; qy += disp[o+1]; qz += disp[o+2];
    }
    const size_t od = (((size_t)mod*BB + b)*NN + n)*3;
    const float dxp = disp[od+0], dyp = disp[od+1], dzp = disp[od+2];
    float nstd = 0.0f;
    if (mod == 0) nstd = stds[b]*0.25f; else if (mod == 1) nstd = stds[b]*0.0625f;
    const bool nt = (mod < 2);
    const float m2x = -2.0f*qx, m2y = -2.0f*qy, m2z = -2.0f*qz;
    float best = INFINITY; int bestm = 0;
    for (int mt = 0; mt < MM; mt += TM) {
        __syncthreads();
        for (int k = tid; k < TM; k += TPB) {
            const int m = mt + k;
            const size_t oc = ((size_t)b*MM + m)*3;
            float tx = clean[oc+0]-sx, ty = clean[oc+1]-sy, tz = clean[oc+2]-sz;
            if (nt) {
                const size_t on = (((size_t)mod*BB + b)*MM + m)*3;
                tx = fmaf(noise[on+0], nstd, tx);
                ty = fmaf(noise[on+1], nstd, ty);
                tz = fmaf(noise[on+2], nstd, tz);
            }
            tgt[k] = make_float4(tx, ty, tz, fmaf(tx,tx,fmaf(ty,ty,tz*tz)));
        }
        __syncthreads();
        #pragma unroll 8
        for (int k = 0; k < TM; ++k) {
            const float4 t = tgt[k];
            const float d2 = fmaf(m2x, t.x, fmaf(m2y, t.y, fmaf(m2z, t.z, t.w)));
            if (d2 < best) { best = d2; bestm = mt + k; }
        }
    }
    const size_t oc = ((size_t)b*MM + bestm)*3;
    float tx = clean[oc+0]-sx, ty = clean[oc+1]-sy, tz = clean[oc+2]-sz;
    if (nt) {
        const size_t on = (((size_t)mod*BB + b)*MM + bestm)*3;
        tx = fmaf(noise[on+0], nstd, tx);
        ty = fmaf(noise[on+1], nstd, ty);
        tz = fmaf(noise[on+2], nstd, tz);
    }
    const float ex = dxp - (tx - qx), ey = dyp - (ty - qy), ez = dzp - (tz - qz);
    float v = fmaf(ex, ex, fmaf(ey, ey, ez*ez));
    for (int o = 32; o; o >>= 1) v += __shfl_down(v, o);
    if ((tid & 63) == 0) red[tid >> 6] = v;
    __syncthreads();
    if (tid == 0)
        partials[(((size_t)mod*BB + b)*NXBLK2) + blockIdx.x] = red[0]+red[1]+red[2]+red[3];
}

extern "C" void kernel_launch(void* const* d_in, const int* in_sizes, int n_in,
                              void* d_out, int out_size, void* d_ws, size_t ws_size,
                              hipStream_t stream) {
    const float* noisy = (const float*)d_in[0];
    const float* clean = (const float*)d_in[1];
    const float* seeds = (const float*)d_in[2];
    const float* stds  = (const float*)d_in[3];
    const float* disp  = (const float*)d_in[4];
    const float* noise = (const float*)d_in[5];
    float* out = (float*)d_out;

    if (ws_size >= WS_NEED) {
        unsigned long long* keys = (unsigned long long*)d_ws;
        float* partials = (float*)((char*)d_ws + KEYB);
        hipMemsetAsync(d_ws, 0xFF, KEYB, stream);
        dim3 g1(NXB, BB, NMOD * SLICES);
        nn_min_kernel<<<g1, TPB, 0, stream>>>(noisy, clean, seeds, stds, disp, noise, keys);
        dim3 g2(NXBLK2, BB, NMOD);
        nn_loss_pass2<<<g2, TPB, 0, stream>>>(noisy, clean, seeds, stds, disp, noise, keys, partials);
        finalize_kernel<<<1, 64, 0, stream>>>(partials, out);
    } else {
        float* partials = (float*)d_ws;
        dim3 grid(NXBLK2, BB, NMOD);
        nn_loss_kernel<<<grid, TPB, 0, stream>>>(noisy, clean, seeds, stds, disp, noise, partials);
        finalize_kernel<<<1, 64, 0, stream>>>(partials, out);
    }
}